// Round 1
// baseline (3897.012 us; speedup 1.0000x reference)
//
#include <hip/hip_runtime.h>
#include <hip/hip_bf16.h>

// ---------------------------------------------------------------------------
// Stage A: _x = x @ W_down + b_down    [N,256]@[256,64] -> [N,64]
// block 256 = 4 nodes x 64 cols
// ---------------------------------------------------------------------------
__global__ __launch_bounds__(256) void k_down(
    const float* __restrict__ x, const float* __restrict__ Wd,
    const float* __restrict__ bd, float* __restrict__ xp, int N)
{
    __shared__ float xs[4][256];
    int n0 = blockIdx.x * 4;
    int tid = threadIdx.x;
    for (int t = tid; t < 4 * 256; t += 256) {
        int rr = t >> 8, kk = t & 255;
        int n = n0 + rr;
        xs[rr][kk] = (n < N) ? x[(size_t)n * 256 + kk] : 0.f;
    }
    __syncthreads();
    int c = tid & 63;
    int r = tid >> 6;
    float acc = bd[c];
    for (int k = 0; k < 256; k += 4) {
        const float4 xv = *(const float4*)&xs[r][k];
        acc += xv.x * Wd[(k + 0) * 64 + c];
        acc += xv.y * Wd[(k + 1) * 64 + c];
        acc += xv.z * Wd[(k + 2) * 64 + c];
        acc += xv.w * Wd[(k + 3) * 64 + c];
    }
    int n = n0 + r;
    if (n < N) xp[(size_t)n * 64 + c] = acc;
}

// ---------------------------------------------------------------------------
// Stage B: edge scatter.  l0_pair = _x[j]*rbf*factor; atomically accumulate
// agg0[i] (+ sph_v1-weighted agg1[i,3], sph_v0-weighted aggh[i,5]).
// block 256 = 4 edges x 64 channels
// ---------------------------------------------------------------------------
__global__ __launch_bounds__(256) void k_edge(
    const float* __restrict__ xp, const float* __restrict__ rbf,
    const float* __restrict__ factor, const float* __restrict__ sph0,
    const float* __restrict__ sph1, const int* __restrict__ jidx,
    const int* __restrict__ iidx,
    float* __restrict__ agg0, float* __restrict__ agg1,
    float* __restrict__ aggh, int E)
{
    int e = blockIdx.x * 4 + (threadIdx.x >> 6);
    if (e >= E) return;
    int p = threadIdx.x & 63;
    int jj = jidx[e];
    int ii = iidx[e];
    float f = factor[e];
    float v = xp[(size_t)jj * 64 + p] * rbf[(size_t)e * 64 + p] * f;

    atomicAdd(&agg0[(size_t)ii * 64 + p], v);

    float s10 = sph1[e * 3 + 0], s11 = sph1[e * 3 + 1], s12 = sph1[e * 3 + 2];
    atomicAdd(&agg1[((size_t)ii * 3 + 0) * 64 + p], v * s10);
    atomicAdd(&agg1[((size_t)ii * 3 + 1) * 64 + p], v * s11);
    atomicAdd(&agg1[((size_t)ii * 3 + 2) * 64 + p], v * s12);

    float s00 = sph0[e * 5 + 0], s01 = sph0[e * 5 + 1], s02 = sph0[e * 5 + 2];
    float s03 = sph0[e * 5 + 3], s04 = sph0[e * 5 + 4];
    atomicAdd(&aggh[((size_t)ii * 5 + 0) * 64 + p], v * s00);
    atomicAdd(&aggh[((size_t)ii * 5 + 1) * 64 + p], v * s01);
    atomicAdd(&aggh[((size_t)ii * 5 + 2) * 64 + p], v * s02);
    atomicAdd(&aggh[((size_t)ii * 5 + 3) * 64 + p], v * s03);
    atomicAdd(&aggh[((size_t)ii * 5 + 4) * 64 + p], v * s04);
}

// ---------------------------------------------------------------------------
// Stage C1: node features -> node[N,384]
//   l0 = (_x*agg0)@W_up0 + b_up0
//   l1 = sum_c ((_x*agg1_c)@W_up1)^2   (c=0..2)
//   lh = sum_c ((_x*aggh_c)@W_uph)^2   (c=0..4)
// block 256, 16 nodes/block; thread = (col 0..127, row-group 0..1 of 8 rows)
// ---------------------------------------------------------------------------
#define C1_NODES 16
__global__ __launch_bounds__(256) void k_node(
    const float* __restrict__ xp, const float* __restrict__ agg0,
    const float* __restrict__ agg1, const float* __restrict__ aggh,
    const float* __restrict__ Wu0, const float* __restrict__ bu0,
    const float* __restrict__ Wu1, const float* __restrict__ Wuh,
    float* __restrict__ node, int N)
{
    __shared__ float xs[C1_NODES * 64];
    __shared__ float a0s[C1_NODES * 64];
    __shared__ float a1s[C1_NODES * 3 * 64];
    __shared__ float ahs[C1_NODES * 5 * 64];
    int n0 = blockIdx.x * C1_NODES;
    int tid = threadIdx.x;

    for (int t = tid; t < C1_NODES * 64; t += 256) {
        int n = n0 + (t >> 6);
        xs[t] = (n < N) ? xp[(size_t)n * 64 + (t & 63)] : 0.f;
    }
    __syncthreads();
    for (int t = tid; t < C1_NODES * 64; t += 256) {
        int n = n0 + (t >> 6);
        a0s[t] = (n < N) ? xs[t] * agg0[(size_t)n * 64 + (t & 63)] : 0.f;
    }
    for (int t = tid; t < C1_NODES * 192; t += 256) {
        int r = t / 192, rem = t - r * 192;
        int n = n0 + r;
        a1s[t] = (n < N) ? xs[r * 64 + (rem & 63)] * agg1[(size_t)n * 192 + rem] : 0.f;
    }
    for (int t = tid; t < C1_NODES * 320; t += 256) {
        int r = t / 320, rem = t - r * 320;
        int n = n0 + r;
        ahs[t] = (n < N) ? xs[r * 64 + (rem & 63)] * aggh[(size_t)n * 320 + rem] : 0.f;
    }
    __syncthreads();

    int c = tid & 127;
    int g = tid >> 7;
    int r0 = g * 8;

    // ---- l0 ----
    float l0[8];
    {
        float bias = bu0[c];
#pragma unroll
        for (int r = 0; r < 8; r++) l0[r] = bias;
        for (int p = 0; p < 64; p += 4) {
            float w0 = Wu0[(p + 0) * 128 + c];
            float w1 = Wu0[(p + 1) * 128 + c];
            float w2 = Wu0[(p + 2) * 128 + c];
            float w3 = Wu0[(p + 3) * 128 + c];
#pragma unroll
            for (int r = 0; r < 8; r++) {
                const float4 av = *(const float4*)&a0s[(r0 + r) * 64 + p];
                l0[r] += av.x * w0 + av.y * w1 + av.z * w2 + av.w * w3;
            }
        }
    }
    // ---- l1 ----
    float l1[8];
#pragma unroll
    for (int r = 0; r < 8; r++) l1[r] = 0.f;
    for (int cc = 0; cc < 3; cc++) {
        float dot[8];
#pragma unroll
        for (int r = 0; r < 8; r++) dot[r] = 0.f;
        for (int p = 0; p < 64; p += 4) {
            float w0 = Wu1[(p + 0) * 128 + c];
            float w1 = Wu1[(p + 1) * 128 + c];
            float w2 = Wu1[(p + 2) * 128 + c];
            float w3 = Wu1[(p + 3) * 128 + c];
#pragma unroll
            for (int r = 0; r < 8; r++) {
                const float4 av = *(const float4*)&a1s[((r0 + r) * 3 + cc) * 64 + p];
                dot[r] += av.x * w0 + av.y * w1 + av.z * w2 + av.w * w3;
            }
        }
#pragma unroll
        for (int r = 0; r < 8; r++) l1[r] += dot[r] * dot[r];
    }
    // ---- lh ----
    float lh[8];
#pragma unroll
    for (int r = 0; r < 8; r++) lh[r] = 0.f;
    for (int cc = 0; cc < 5; cc++) {
        float dot[8];
#pragma unroll
        for (int r = 0; r < 8; r++) dot[r] = 0.f;
        for (int p = 0; p < 64; p += 4) {
            float w0 = Wuh[(p + 0) * 128 + c];
            float w1 = Wuh[(p + 1) * 128 + c];
            float w2 = Wuh[(p + 2) * 128 + c];
            float w3 = Wuh[(p + 3) * 128 + c];
#pragma unroll
            for (int r = 0; r < 8; r++) {
                const float4 av = *(const float4*)&ahs[((r0 + r) * 5 + cc) * 64 + p];
                dot[r] += av.x * w0 + av.y * w1 + av.z * w2 + av.w * w3;
            }
        }
#pragma unroll
        for (int r = 0; r < 8; r++) lh[r] += dot[r] * dot[r];
    }
    // ---- store ----
#pragma unroll
    for (int r = 0; r < 8; r++) {
        int n = n0 + r0 + r;
        if (n < N) {
            node[(size_t)n * 384 + c]       = l0[r];
            node[(size_t)n * 384 + 128 + c] = l1[r];
            node[(size_t)n * 384 + 256 + c] = lh[r];
        }
    }
}

// ---------------------------------------------------------------------------
// Stage C2 (fused): t = node@W_n1 + b_n1; h = silu(LN(t)); out = h@W_n2+b_n2+x
// block 256, 32 nodes/block; thread = (col-pair c2/c2+128, row-group of 16)
// ---------------------------------------------------------------------------
#define C2_ROWS 32
__global__ __launch_bounds__(256) void k_final(
    const float* __restrict__ node, const float* __restrict__ Wn1,
    const float* __restrict__ bn1, const float* __restrict__ lng,
    const float* __restrict__ lnb, const float* __restrict__ Wn2,
    const float* __restrict__ bn2, const float* __restrict__ x,
    float* __restrict__ out, int N)
{
    __shared__ float As[C2_ROWS][32];
    __shared__ float Hs[C2_ROWS][256];
    __shared__ float red[C2_ROWS][8];
    __shared__ float red2[C2_ROWS][8];
    __shared__ float mstat[C2_ROWS][2];

    int n0 = blockIdx.x * C2_ROWS;
    int tid = threadIdx.x;
    int c2 = tid & 127;
    int g = tid >> 7;
    int r0 = g * 16;

    float acc0[16], acc1[16];
#pragma unroll
    for (int r = 0; r < 16; r++) { acc0[r] = 0.f; acc1[r] = 0.f; }

    for (int k0 = 0; k0 < 384; k0 += 32) {
        for (int t = tid; t < C2_ROWS * 32; t += 256) {
            int r = t >> 5, k = t & 31;
            int n = n0 + r;
            As[r][k] = (n < N) ? node[(size_t)n * 384 + k0 + k] : 0.f;
        }
        __syncthreads();
        for (int k = 0; k < 32; k += 4) {
            float w00 = Wn1[(k0 + k + 0) * 256 + c2];
            float w01 = Wn1[(k0 + k + 1) * 256 + c2];
            float w02 = Wn1[(k0 + k + 2) * 256 + c2];
            float w03 = Wn1[(k0 + k + 3) * 256 + c2];
            float w10 = Wn1[(k0 + k + 0) * 256 + c2 + 128];
            float w11 = Wn1[(k0 + k + 1) * 256 + c2 + 128];
            float w12 = Wn1[(k0 + k + 2) * 256 + c2 + 128];
            float w13 = Wn1[(k0 + k + 3) * 256 + c2 + 128];
#pragma unroll
            for (int r = 0; r < 16; r++) {
                const float4 av = *(const float4*)&As[r0 + r][k];
                acc0[r] += av.x * w00 + av.y * w01 + av.z * w02 + av.w * w03;
                acc1[r] += av.x * w10 + av.y * w11 + av.z * w12 + av.w * w13;
            }
        }
        __syncthreads();
    }

    // pre-LN values into Hs
    {
        float b0 = bn1[c2], b1 = bn1[c2 + 128];
#pragma unroll
        for (int r = 0; r < 16; r++) {
            Hs[r0 + r][c2]       = acc0[r] + b0;
            Hs[r0 + r][c2 + 128] = acc1[r] + b1;
        }
    }
    __syncthreads();

    // per-row mean / var (8 threads per row)
    {
        int row = tid >> 3, seg = tid & 7;
        float s = 0.f, s2 = 0.f;
#pragma unroll
        for (int k = 0; k < 32; k += 4) {
            const float4 v = *(const float4*)&Hs[row][seg * 32 + k];
            s  += v.x + v.y + v.z + v.w;
            s2 += v.x * v.x + v.y * v.y + v.z * v.z + v.w * v.w;
        }
        red[row][seg] = s;
        red2[row][seg] = s2;
    }
    __syncthreads();
    if (tid < C2_ROWS) {
        float s = 0.f, s2 = 0.f;
#pragma unroll
        for (int q = 0; q < 8; q++) { s += red[tid][q]; s2 += red2[tid][q]; }
        float m = s * (1.f / 256.f);
        float var = s2 * (1.f / 256.f) - m * m;
        mstat[tid][0] = m;
        mstat[tid][1] = rsqrtf(var + 1e-5f);
    }
    __syncthreads();

    // LN + SiLU in place
    {
        float g0 = lng[c2], g1 = lng[c2 + 128];
        float bb0 = lnb[c2], bb1 = lnb[c2 + 128];
#pragma unroll
        for (int r = 0; r < 16; r++) {
            int row = r0 + r;
            float m = mstat[row][0], is = mstat[row][1];
            float z0 = (Hs[row][c2] - m) * is * g0 + bb0;
            float z1 = (Hs[row][c2 + 128] - m) * is * g1 + bb1;
            Hs[row][c2]       = z0 / (1.f + __expf(-z0));
            Hs[row][c2 + 128] = z1 / (1.f + __expf(-z1));
        }
    }
    __syncthreads();

    // GEMM2: out = h @ W_n2 + b_n2 + x
    float o0[16], o1[16];
#pragma unroll
    for (int r = 0; r < 16; r++) { o0[r] = 0.f; o1[r] = 0.f; }
    for (int k = 0; k < 256; k += 4) {
        float w00 = Wn2[(k + 0) * 256 + c2];
        float w01 = Wn2[(k + 1) * 256 + c2];
        float w02 = Wn2[(k + 2) * 256 + c2];
        float w03 = Wn2[(k + 3) * 256 + c2];
        float w10 = Wn2[(k + 0) * 256 + c2 + 128];
        float w11 = Wn2[(k + 1) * 256 + c2 + 128];
        float w12 = Wn2[(k + 2) * 256 + c2 + 128];
        float w13 = Wn2[(k + 3) * 256 + c2 + 128];
#pragma unroll
        for (int r = 0; r < 16; r++) {
            const float4 av = *(const float4*)&Hs[r0 + r][k];
            o0[r] += av.x * w00 + av.y * w01 + av.z * w02 + av.w * w03;
            o1[r] += av.x * w10 + av.y * w11 + av.z * w12 + av.w * w13;
        }
    }
    {
        float ob0 = bn2[c2], ob1 = bn2[c2 + 128];
#pragma unroll
        for (int r = 0; r < 16; r++) {
            int n = n0 + r0 + r;
            if (n < N) {
                out[(size_t)n * 256 + c2]       = o0[r] + ob0 + x[(size_t)n * 256 + c2];
                out[(size_t)n * 256 + c2 + 128] = o1[r] + ob1 + x[(size_t)n * 256 + c2 + 128];
            }
        }
    }
}

// ---------------------------------------------------------------------------
extern "C" void kernel_launch(void* const* d_in, const int* in_sizes, int n_in,
                              void* d_out, int out_size, void* d_ws, size_t ws_size,
                              hipStream_t stream)
{
    const float* x      = (const float*)d_in[0];
    const float* rbf    = (const float*)d_in[1];
    const float* factor = (const float*)d_in[2];
    const float* sph0   = (const float*)d_in[3];
    const float* sph1   = (const float*)d_in[4];
    const float* Wd     = (const float*)d_in[5];
    const float* bd     = (const float*)d_in[6];
    const float* Wu0    = (const float*)d_in[7];
    const float* bu0    = (const float*)d_in[8];
    const float* Wu1    = (const float*)d_in[9];
    const float* Wuh    = (const float*)d_in[10];
    const float* Wn1    = (const float*)d_in[11];
    const float* bn1    = (const float*)d_in[12];
    const float* lng    = (const float*)d_in[13];
    const float* lnb    = (const float*)d_in[14];
    const float* Wn2    = (const float*)d_in[15];
    const float* bn2    = (const float*)d_in[16];
    const int*   jidx   = (const int*)d_in[17];
    const int*   iidx   = (const int*)d_in[18];
    float* out = (float*)d_out;

    int N = in_sizes[0] / 256;
    int E = in_sizes[17];

    float* ws   = (float*)d_ws;
    float* xp   = ws;                        // [N,64]
    float* agg0 = xp   + (size_t)N * 64;     // [N,64]
    float* agg1 = agg0 + (size_t)N * 64;     // [N,3,64]
    float* aggh = agg1 + (size_t)N * 192;    // [N,5,64]
    float* node = aggh + (size_t)N * 320;    // [N,384]

    hipMemsetAsync(agg0, 0, (size_t)N * 576 * sizeof(float), stream);

    k_down<<<dim3((N + 3) / 4), dim3(256), 0, stream>>>(x, Wd, bd, xp, N);
    k_edge<<<dim3((E + 3) / 4), dim3(256), 0, stream>>>(
        xp, rbf, factor, sph0, sph1, jidx, iidx, agg0, agg1, aggh, E);
    k_node<<<dim3((N + C1_NODES - 1) / C1_NODES), dim3(256), 0, stream>>>(
        xp, agg0, agg1, aggh, Wu0, bu0, Wu1, Wuh, node, N);
    k_final<<<dim3((N + C2_ROWS - 1) / C2_ROWS), dim3(256), 0, stream>>>(
        node, Wn1, bn1, lng, lnb, Wn2, bn2, x, out, N);
}

// Round 2
// 3451.152 us; speedup vs baseline: 1.1292x; 1.1292x over previous
//
#include <hip/hip_runtime.h>
#include <hip/hip_bf16.h>

// ---------------------------------------------------------------------------
// Stage A: _x = x @ W_down + b_down    [N,256]@[256,64] -> [N,64]
// block 256 = 4 nodes x 64 cols
// ---------------------------------------------------------------------------
__global__ __launch_bounds__(256) void k_down(
    const float* __restrict__ x, const float* __restrict__ Wd,
    const float* __restrict__ bd, float* __restrict__ xp, int N)
{
    __shared__ float xs[4][256];
    int n0 = blockIdx.x * 4;
    int tid = threadIdx.x;
    for (int t = tid; t < 4 * 256; t += 256) {
        int rr = t >> 8, kk = t & 255;
        int n = n0 + rr;
        xs[rr][kk] = (n < N) ? x[(size_t)n * 256 + kk] : 0.f;
    }
    __syncthreads();
    int c = tid & 63;
    int r = tid >> 6;
    float acc = bd[c];
    for (int k = 0; k < 256; k += 4) {
        const float4 xv = *(const float4*)&xs[r][k];
        acc += xv.x * Wd[(k + 0) * 64 + c];
        acc += xv.y * Wd[(k + 1) * 64 + c];
        acc += xv.z * Wd[(k + 2) * 64 + c];
        acc += xv.w * Wd[(k + 3) * 64 + c];
    }
    int n = n0 + r;
    if (n < N) xp[(size_t)n * 64 + c] = acc;
}

// ---------------------------------------------------------------------------
// Stage B: edge scatter.  l0_pair = _x[j]*rbf*factor; atomically accumulate
// agg0[i] (+ sph_v1-weighted agg1[i,3], sph_v0-weighted aggh[i,5]).
// block 256 = 4 edges x 64 channels
// ---------------------------------------------------------------------------
__global__ __launch_bounds__(256) void k_edge(
    const float* __restrict__ xp, const float* __restrict__ rbf,
    const float* __restrict__ factor, const float* __restrict__ sph0,
    const float* __restrict__ sph1, const int* __restrict__ jidx,
    const int* __restrict__ iidx,
    float* __restrict__ agg0, float* __restrict__ agg1,
    float* __restrict__ aggh, int E)
{
    int e = blockIdx.x * 4 + (threadIdx.x >> 6);
    if (e >= E) return;
    int p = threadIdx.x & 63;
    int jj = jidx[e];
    int ii = iidx[e];
    float f = factor[e];
    float v = xp[(size_t)jj * 64 + p] * rbf[(size_t)e * 64 + p] * f;

    atomicAdd(&agg0[(size_t)ii * 64 + p], v);

    float s10 = sph1[e * 3 + 0], s11 = sph1[e * 3 + 1], s12 = sph1[e * 3 + 2];
    atomicAdd(&agg1[((size_t)ii * 3 + 0) * 64 + p], v * s10);
    atomicAdd(&agg1[((size_t)ii * 3 + 1) * 64 + p], v * s11);
    atomicAdd(&agg1[((size_t)ii * 3 + 2) * 64 + p], v * s12);

    float s00 = sph0[e * 5 + 0], s01 = sph0[e * 5 + 1], s02 = sph0[e * 5 + 2];
    float s03 = sph0[e * 5 + 3], s04 = sph0[e * 5 + 4];
    atomicAdd(&aggh[((size_t)ii * 5 + 0) * 64 + p], v * s00);
    atomicAdd(&aggh[((size_t)ii * 5 + 1) * 64 + p], v * s01);
    atomicAdd(&aggh[((size_t)ii * 5 + 2) * 64 + p], v * s02);
    atomicAdd(&aggh[((size_t)ii * 5 + 3) * 64 + p], v * s03);
    atomicAdd(&aggh[((size_t)ii * 5 + 4) * 64 + p], v * s04);
}

// ---------------------------------------------------------------------------
// Stage C1: node features -> node[N,384]
//   l0 = (_x*agg0)@W_up0 + b_up0
//   l1 = sum_c ((_x*agg1_c)@W_up1)^2   (c=0..2)
//   lh = sum_c ((_x*aggh_c)@W_uph)^2   (c=0..4)
// block 256, 16 nodes/block; thread = (col pair c/c+64, 4-row group).
// R1 fix: was 1 col x 8 rows/thread -> 256 VGPRs + 5.3 GB spill traffic.
// Now 2 cols x 4 rows/thread; wave lanes differ only in col -> LDS A-reads
// are wave-broadcast (conflict-free) and each ds_read_b128 feeds 8 FMAs.
// ---------------------------------------------------------------------------
#define C1_NODES 16
__global__ __launch_bounds__(256, 4) void k_node(
    const float* __restrict__ xp, const float* __restrict__ agg0,
    const float* __restrict__ agg1, const float* __restrict__ aggh,
    const float* __restrict__ Wu0, const float* __restrict__ bu0,
    const float* __restrict__ Wu1, const float* __restrict__ Wuh,
    float* __restrict__ node, int N)
{
    __shared__ float xs[C1_NODES * 64];
    __shared__ float a0s[C1_NODES * 64];
    __shared__ float a1s[C1_NODES * 3 * 64];
    __shared__ float ahs[C1_NODES * 5 * 64];
    int n0 = blockIdx.x * C1_NODES;
    int tid = threadIdx.x;

    for (int t = tid; t < C1_NODES * 64; t += 256) {
        int n = n0 + (t >> 6);
        xs[t] = (n < N) ? xp[(size_t)n * 64 + (t & 63)] : 0.f;
    }
    __syncthreads();
    for (int t = tid; t < C1_NODES * 64; t += 256) {
        int n = n0 + (t >> 6);
        a0s[t] = (n < N) ? xs[t] * agg0[(size_t)n * 64 + (t & 63)] : 0.f;
    }
    for (int t = tid; t < C1_NODES * 192; t += 256) {
        int r = t / 192, rem = t - r * 192;
        int n = n0 + r;
        a1s[t] = (n < N) ? xs[r * 64 + (rem & 63)] * agg1[(size_t)n * 192 + rem] : 0.f;
    }
    for (int t = tid; t < C1_NODES * 320; t += 256) {
        int r = t / 320, rem = t - r * 320;
        int n = n0 + r;
        ahs[t] = (n < N) ? xs[r * 64 + (rem & 63)] * aggh[(size_t)n * 320 + rem] : 0.f;
    }
    __syncthreads();

    int c = tid & 63;      // owns cols c and c+64 (of 128)
    int g = tid >> 6;      // 0..3
    int r0 = g * 4;        // 4 rows per thread

    // ---- l0 ----
    {
        float a0c[4], a1c[4];
        float b0 = bu0[c], b1 = bu0[c + 64];
#pragma unroll
        for (int r = 0; r < 4; r++) { a0c[r] = b0; a1c[r] = b1; }
        for (int p = 0; p < 64; p += 4) {
            float w00 = Wu0[(p + 0) * 128 + c];
            float w01 = Wu0[(p + 1) * 128 + c];
            float w02 = Wu0[(p + 2) * 128 + c];
            float w03 = Wu0[(p + 3) * 128 + c];
            float w10 = Wu0[(p + 0) * 128 + c + 64];
            float w11 = Wu0[(p + 1) * 128 + c + 64];
            float w12 = Wu0[(p + 2) * 128 + c + 64];
            float w13 = Wu0[(p + 3) * 128 + c + 64];
#pragma unroll
            for (int r = 0; r < 4; r++) {
                const float4 av = *(const float4*)&a0s[(r0 + r) * 64 + p];
                a0c[r] += av.x * w00 + av.y * w01 + av.z * w02 + av.w * w03;
                a1c[r] += av.x * w10 + av.y * w11 + av.z * w12 + av.w * w13;
            }
        }
#pragma unroll
        for (int r = 0; r < 4; r++) {
            int n = n0 + r0 + r;
            if (n < N) {
                node[(size_t)n * 384 + c]      = a0c[r];
                node[(size_t)n * 384 + c + 64] = a1c[r];
            }
        }
    }
    // ---- l1 ----
    {
        float s0[4], s1[4];
#pragma unroll
        for (int r = 0; r < 4; r++) { s0[r] = 0.f; s1[r] = 0.f; }
        for (int cc = 0; cc < 3; cc++) {
            float d0[4], d1[4];
#pragma unroll
            for (int r = 0; r < 4; r++) { d0[r] = 0.f; d1[r] = 0.f; }
            for (int p = 0; p < 64; p += 4) {
                float w00 = Wu1[(p + 0) * 128 + c];
                float w01 = Wu1[(p + 1) * 128 + c];
                float w02 = Wu1[(p + 2) * 128 + c];
                float w03 = Wu1[(p + 3) * 128 + c];
                float w10 = Wu1[(p + 0) * 128 + c + 64];
                float w11 = Wu1[(p + 1) * 128 + c + 64];
                float w12 = Wu1[(p + 2) * 128 + c + 64];
                float w13 = Wu1[(p + 3) * 128 + c + 64];
#pragma unroll
                for (int r = 0; r < 4; r++) {
                    const float4 av = *(const float4*)&a1s[((r0 + r) * 3 + cc) * 64 + p];
                    d0[r] += av.x * w00 + av.y * w01 + av.z * w02 + av.w * w03;
                    d1[r] += av.x * w10 + av.y * w11 + av.z * w12 + av.w * w13;
                }
            }
#pragma unroll
            for (int r = 0; r < 4; r++) { s0[r] += d0[r] * d0[r]; s1[r] += d1[r] * d1[r]; }
        }
#pragma unroll
        for (int r = 0; r < 4; r++) {
            int n = n0 + r0 + r;
            if (n < N) {
                node[(size_t)n * 384 + 128 + c]      = s0[r];
                node[(size_t)n * 384 + 128 + c + 64] = s1[r];
            }
        }
    }
    // ---- lh ----
    {
        float s0[4], s1[4];
#pragma unroll
        for (int r = 0; r < 4; r++) { s0[r] = 0.f; s1[r] = 0.f; }
        for (int cc = 0; cc < 5; cc++) {
            float d0[4], d1[4];
#pragma unroll
            for (int r = 0; r < 4; r++) { d0[r] = 0.f; d1[r] = 0.f; }
            for (int p = 0; p < 64; p += 4) {
                float w00 = Wuh[(p + 0) * 128 + c];
                float w01 = Wuh[(p + 1) * 128 + c];
                float w02 = Wuh[(p + 2) * 128 + c];
                float w03 = Wuh[(p + 3) * 128 + c];
                float w10 = Wuh[(p + 0) * 128 + c + 64];
                float w11 = Wuh[(p + 1) * 128 + c + 64];
                float w12 = Wuh[(p + 2) * 128 + c + 64];
                float w13 = Wuh[(p + 3) * 128 + c + 64];
#pragma unroll
                for (int r = 0; r < 4; r++) {
                    const float4 av = *(const float4*)&ahs[((r0 + r) * 5 + cc) * 64 + p];
                    d0[r] += av.x * w00 + av.y * w01 + av.z * w02 + av.w * w03;
                    d1[r] += av.x * w10 + av.y * w11 + av.z * w12 + av.w * w13;
                }
            }
#pragma unroll
            for (int r = 0; r < 4; r++) { s0[r] += d0[r] * d0[r]; s1[r] += d1[r] * d1[r]; }
        }
#pragma unroll
        for (int r = 0; r < 4; r++) {
            int n = n0 + r0 + r;
            if (n < N) {
                node[(size_t)n * 384 + 256 + c]      = s0[r];
                node[(size_t)n * 384 + 256 + c + 64] = s1[r];
            }
        }
    }
}

// ---------------------------------------------------------------------------
// Stage C2 (fused): t = node@W_n1 + b_n1; h = silu(LN(t)); out = h@W_n2+b_n2+x
// block 256, 32 nodes/block; thread = (col-pair c2/c2+128, row-group of 16)
// ---------------------------------------------------------------------------
#define C2_ROWS 32
__global__ __launch_bounds__(256) void k_final(
    const float* __restrict__ node, const float* __restrict__ Wn1,
    const float* __restrict__ bn1, const float* __restrict__ lng,
    const float* __restrict__ lnb, const float* __restrict__ Wn2,
    const float* __restrict__ bn2, const float* __restrict__ x,
    float* __restrict__ out, int N)
{
    __shared__ float As[C2_ROWS][32];
    __shared__ float Hs[C2_ROWS][256];
    __shared__ float red[C2_ROWS][8];
    __shared__ float red2[C2_ROWS][8];
    __shared__ float mstat[C2_ROWS][2];

    int n0 = blockIdx.x * C2_ROWS;
    int tid = threadIdx.x;
    int c2 = tid & 127;
    int g = tid >> 7;
    int r0 = g * 16;

    float acc0[16], acc1[16];
#pragma unroll
    for (int r = 0; r < 16; r++) { acc0[r] = 0.f; acc1[r] = 0.f; }

    for (int k0 = 0; k0 < 384; k0 += 32) {
        for (int t = tid; t < C2_ROWS * 32; t += 256) {
            int r = t >> 5, k = t & 31;
            int n = n0 + r;
            As[r][k] = (n < N) ? node[(size_t)n * 384 + k0 + k] : 0.f;
        }
        __syncthreads();
        for (int k = 0; k < 32; k += 4) {
            float w00 = Wn1[(k0 + k + 0) * 256 + c2];
            float w01 = Wn1[(k0 + k + 1) * 256 + c2];
            float w02 = Wn1[(k0 + k + 2) * 256 + c2];
            float w03 = Wn1[(k0 + k + 3) * 256 + c2];
            float w10 = Wn1[(k0 + k + 0) * 256 + c2 + 128];
            float w11 = Wn1[(k0 + k + 1) * 256 + c2 + 128];
            float w12 = Wn1[(k0 + k + 2) * 256 + c2 + 128];
            float w13 = Wn1[(k0 + k + 3) * 256 + c2 + 128];
#pragma unroll
            for (int r = 0; r < 16; r++) {
                const float4 av = *(const float4*)&As[r0 + r][k];
                acc0[r] += av.x * w00 + av.y * w01 + av.z * w02 + av.w * w03;
                acc1[r] += av.x * w10 + av.y * w11 + av.z * w12 + av.w * w13;
            }
        }
        __syncthreads();
    }

    // pre-LN values into Hs
    {
        float b0 = bn1[c2], b1 = bn1[c2 + 128];
#pragma unroll
        for (int r = 0; r < 16; r++) {
            Hs[r0 + r][c2]       = acc0[r] + b0;
            Hs[r0 + r][c2 + 128] = acc1[r] + b1;
        }
    }
    __syncthreads();

    // per-row mean / var (8 threads per row)
    {
        int row = tid >> 3, seg = tid & 7;
        float s = 0.f, s2 = 0.f;
#pragma unroll
        for (int k = 0; k < 32; k += 4) {
            const float4 v = *(const float4*)&Hs[row][seg * 32 + k];
            s  += v.x + v.y + v.z + v.w;
            s2 += v.x * v.x + v.y * v.y + v.z * v.z + v.w * v.w;
        }
        red[row][seg] = s;
        red2[row][seg] = s2;
    }
    __syncthreads();
    if (tid < C2_ROWS) {
        float s = 0.f, s2 = 0.f;
#pragma unroll
        for (int q = 0; q < 8; q++) { s += red[tid][q]; s2 += red2[tid][q]; }
        float m = s * (1.f / 256.f);
        float var = s2 * (1.f / 256.f) - m * m;
        mstat[tid][0] = m;
        mstat[tid][1] = rsqrtf(var + 1e-5f);
    }
    __syncthreads();

    // LN + SiLU in place
    {
        float g0 = lng[c2], g1 = lng[c2 + 128];
        float bb0 = lnb[c2], bb1 = lnb[c2 + 128];
#pragma unroll
        for (int r = 0; r < 16; r++) {
            int row = r0 + r;
            float m = mstat[row][0], is = mstat[row][1];
            float z0 = (Hs[row][c2] - m) * is * g0 + bb0;
            float z1 = (Hs[row][c2 + 128] - m) * is * g1 + bb1;
            Hs[row][c2]       = z0 / (1.f + __expf(-z0));
            Hs[row][c2 + 128] = z1 / (1.f + __expf(-z1));
        }
    }
    __syncthreads();

    // GEMM2: out = h @ W_n2 + b_n2 + x
    float o0[16], o1[16];
#pragma unroll
    for (int r = 0; r < 16; r++) { o0[r] = 0.f; o1[r] = 0.f; }
    for (int k = 0; k < 256; k += 4) {
        float w00 = Wn2[(k + 0) * 256 + c2];
        float w01 = Wn2[(k + 1) * 256 + c2];
        float w02 = Wn2[(k + 2) * 256 + c2];
        float w03 = Wn2[(k + 3) * 256 + c2];
        float w10 = Wn2[(k + 0) * 256 + c2 + 128];
        float w11 = Wn2[(k + 1) * 256 + c2 + 128];
        float w12 = Wn2[(k + 2) * 256 + c2 + 128];
        float w13 = Wn2[(k + 3) * 256 + c2 + 128];
#pragma unroll
        for (int r = 0; r < 16; r++) {
            const float4 av = *(const float4*)&Hs[r0 + r][k];
            o0[r] += av.x * w00 + av.y * w01 + av.z * w02 + av.w * w03;
            o1[r] += av.x * w10 + av.y * w11 + av.z * w12 + av.w * w13;
        }
    }
    {
        float ob0 = bn2[c2], ob1 = bn2[c2 + 128];
#pragma unroll
        for (int r = 0; r < 16; r++) {
            int n = n0 + r0 + r;
            if (n < N) {
                out[(size_t)n * 256 + c2]       = o0[r] + ob0 + x[(size_t)n * 256 + c2];
                out[(size_t)n * 256 + c2 + 128] = o1[r] + ob1 + x[(size_t)n * 256 + c2 + 128];
            }
        }
    }
}

// ---------------------------------------------------------------------------
extern "C" void kernel_launch(void* const* d_in, const int* in_sizes, int n_in,
                              void* d_out, int out_size, void* d_ws, size_t ws_size,
                              hipStream_t stream)
{
    const float* x      = (const float*)d_in[0];
    const float* rbf    = (const float*)d_in[1];
    const float* factor = (const float*)d_in[2];
    const float* sph0   = (const float*)d_in[3];
    const float* sph1   = (const float*)d_in[4];
    const float* Wd     = (const float*)d_in[5];
    const float* bd     = (const float*)d_in[6];
    const float* Wu0    = (const float*)d_in[7];
    const float* bu0    = (const float*)d_in[8];
    const float* Wu1    = (const float*)d_in[9];
    const float* Wuh    = (const float*)d_in[10];
    const float* Wn1    = (const float*)d_in[11];
    const float* bn1    = (const float*)d_in[12];
    const float* lng    = (const float*)d_in[13];
    const float* lnb    = (const float*)d_in[14];
    const float* Wn2    = (const float*)d_in[15];
    const float* bn2    = (const float*)d_in[16];
    const int*   jidx   = (const int*)d_in[17];
    const int*   iidx   = (const int*)d_in[18];
    float* out = (float*)d_out;

    int N = in_sizes[0] / 256;
    int E = in_sizes[17];

    float* ws   = (float*)d_ws;
    float* xp   = ws;                        // [N,64]
    float* agg0 = xp   + (size_t)N * 64;     // [N,64]
    float* agg1 = agg0 + (size_t)N * 64;     // [N,3,64]
    float* aggh = agg1 + (size_t)N * 192;    // [N,5,64]
    float* node = aggh + (size_t)N * 320;    // [N,384]

    hipMemsetAsync(agg0, 0, (size_t)N * 576 * sizeof(float), stream);

    k_down<<<dim3((N + 3) / 4), dim3(256), 0, stream>>>(x, Wd, bd, xp, N);
    k_edge<<<dim3((E + 3) / 4), dim3(256), 0, stream>>>(
        xp, rbf, factor, sph0, sph1, jidx, iidx, agg0, agg1, aggh, E);
    k_node<<<dim3((N + C1_NODES - 1) / C1_NODES), dim3(256), 0, stream>>>(
        xp, agg0, agg1, aggh, Wu0, bu0, Wu1, Wuh, node, N);
    k_final<<<dim3((N + C2_ROWS - 1) / C2_ROWS), dim3(256), 0, stream>>>(
        node, Wn1, bn1, lng, lnb, Wn2, bn2, x, out, N);
}

// Round 3
// 1638.828 us; speedup vs baseline: 2.3779x; 2.1059x over previous
//
#include <hip/hip_runtime.h>
#include <hip/hip_bf16.h>

// ---------------------------------------------------------------------------
// Stage A: _x = x @ W_down + b_down    [N,256]@[256,64] -> [N,64]
// R2 fix: Wd staged in LDS once per block (was: every wave re-read all 64 KB
// from global -> 1.6 GB fabric traffic). W4 layout [pb][c] = 4 consecutive
// k-rows packed in a float4 -> dense lane-contiguous ds_read_b128.
// block 256 = 8 nodes x (64 cols x 2-row groups); LDS 72 KB -> 2 blocks/CU.
// ---------------------------------------------------------------------------
#define KD_NODES 8
__global__ __launch_bounds__(256) void k_down(
    const float* __restrict__ x, const float* __restrict__ Wd,
    const float* __restrict__ bd, float* __restrict__ xp, int N)
{
    __shared__ float xs[KD_NODES][256];   // 8 KB
    __shared__ float4 Ws[64 * 64];        // 64 KB: Ws[pb*64+c] = Wd[4pb+q][c]
    int n0 = blockIdx.x * KD_NODES;
    int tid = threadIdx.x;

    for (int t = tid; t < KD_NODES * 256; t += 256) {
        int rr = t >> 8, kk = t & 255;
        int n = n0 + rr;
        xs[rr][kk] = (n < N) ? x[(size_t)n * 256 + kk] : 0.f;
    }
    for (int t = tid; t < 64 * 64; t += 256) {
        int pb = t >> 6, c = t & 63;
        float4 w;
        w.x = Wd[(4 * pb + 0) * 64 + c];
        w.y = Wd[(4 * pb + 1) * 64 + c];
        w.z = Wd[(4 * pb + 2) * 64 + c];
        w.w = Wd[(4 * pb + 3) * 64 + c];
        Ws[t] = w;
    }
    __syncthreads();

    int c = tid & 63;
    int r0 = (tid >> 6) * 2;
    float a0 = bd[c], a1 = a0;
    for (int pb = 0; pb < 64; pb++) {
        float4 w = Ws[pb * 64 + c];
        const float4 x0 = *(const float4*)&xs[r0][pb * 4];
        const float4 x1 = *(const float4*)&xs[r0 + 1][pb * 4];
        a0 += x0.x * w.x + x0.y * w.y + x0.z * w.z + x0.w * w.w;
        a1 += x1.x * w.x + x1.y * w.y + x1.z * w.z + x1.w * w.w;
    }
    int n = n0 + r0;
    if (n < N)     xp[(size_t)n * 64 + c]       = a0;
    if (n + 1 < N) xp[(size_t)(n + 1) * 64 + c] = a1;
}

// ---------------------------------------------------------------------------
// Stage B: edge scatter (unchanged this round — attribution isolation).
// ---------------------------------------------------------------------------
__global__ __launch_bounds__(256) void k_edge(
    const float* __restrict__ xp, const float* __restrict__ rbf,
    const float* __restrict__ factor, const float* __restrict__ sph0,
    const float* __restrict__ sph1, const int* __restrict__ jidx,
    const int* __restrict__ iidx,
    float* __restrict__ agg0, float* __restrict__ agg1,
    float* __restrict__ aggh, int E)
{
    int e = blockIdx.x * 4 + (threadIdx.x >> 6);
    if (e >= E) return;
    int p = threadIdx.x & 63;
    int jj = jidx[e];
    int ii = iidx[e];
    float f = factor[e];
    float v = xp[(size_t)jj * 64 + p] * rbf[(size_t)e * 64 + p] * f;

    atomicAdd(&agg0[(size_t)ii * 64 + p], v);

    float s10 = sph1[e * 3 + 0], s11 = sph1[e * 3 + 1], s12 = sph1[e * 3 + 2];
    atomicAdd(&agg1[((size_t)ii * 3 + 0) * 64 + p], v * s10);
    atomicAdd(&agg1[((size_t)ii * 3 + 1) * 64 + p], v * s11);
    atomicAdd(&agg1[((size_t)ii * 3 + 2) * 64 + p], v * s12);

    float s00 = sph0[e * 5 + 0], s01 = sph0[e * 5 + 1], s02 = sph0[e * 5 + 2];
    float s03 = sph0[e * 5 + 3], s04 = sph0[e * 5 + 4];
    atomicAdd(&aggh[((size_t)ii * 5 + 0) * 64 + p], v * s00);
    atomicAdd(&aggh[((size_t)ii * 5 + 1) * 64 + p], v * s01);
    atomicAdd(&aggh[((size_t)ii * 5 + 2) * 64 + p], v * s02);
    atomicAdd(&aggh[((size_t)ii * 5 + 3) * 64 + p], v * s03);
    atomicAdd(&aggh[((size_t)ii * 5 + 4) * 64 + p], v * s04);
}

// ---------------------------------------------------------------------------
// Stage C1: node features -> node[N,384]
// R2 fix: weights staged in LDS once per block into a single reused 32 KB
// buffer (Wu0 -> l0, Wu1 -> l1, Wuh -> lh, barrier-separated). Was: every
// wave re-read 288 KB of weights from global (1.8 GB grid-wide, L2-thrashed).
// Main loop: weights = dense lane-contiguous ds_read_b128; A = wave-broadcast
// ds_read_b128; 32 v_fma per iteration -> VALU-bound.
// LDS: 40 KB A-tiles + 32 KB weights = 72 KB -> 2 blocks/CU.
// ---------------------------------------------------------------------------
#define C1_NODES 16
__global__ __launch_bounds__(256) void k_node(
    const float* __restrict__ xp, const float* __restrict__ agg0,
    const float* __restrict__ agg1, const float* __restrict__ aggh,
    const float* __restrict__ Wu0, const float* __restrict__ bu0,
    const float* __restrict__ Wu1, const float* __restrict__ Wuh,
    float* __restrict__ node, int N)
{
    __shared__ float xs[C1_NODES * 64];        // 4 KB
    __shared__ float a0s[C1_NODES * 64];       // 4 KB
    __shared__ float a1s[C1_NODES * 3 * 64];   // 12 KB
    __shared__ float ahs[C1_NODES * 5 * 64];   // 20 KB
    __shared__ float4 Ws[16 * 128];            // 32 KB: Ws[pb*128+c] = W[4pb+q][c]
    int n0 = blockIdx.x * C1_NODES;
    int tid = threadIdx.x;

    // ---- stage _x ----
    for (int t = tid; t < C1_NODES * 64; t += 256) {
        int n = n0 + (t >> 6);
        xs[t] = (n < N) ? xp[(size_t)n * 64 + (t & 63)] : 0.f;
    }
    __syncthreads();
    // ---- build premultiplied A-tiles + stage Wu0 ----
    for (int t = tid; t < C1_NODES * 64; t += 256) {
        int n = n0 + (t >> 6);
        a0s[t] = (n < N) ? xs[t] * agg0[(size_t)n * 64 + (t & 63)] : 0.f;
    }
    for (int t = tid; t < C1_NODES * 192; t += 256) {
        int r = t / 192, rem = t - r * 192;
        int n = n0 + r;
        a1s[t] = (n < N) ? xs[r * 64 + (rem & 63)] * agg1[(size_t)n * 192 + rem] : 0.f;
    }
    for (int t = tid; t < C1_NODES * 320; t += 256) {
        int r = t / 320, rem = t - r * 320;
        int n = n0 + r;
        ahs[t] = (n < N) ? xs[r * 64 + (rem & 63)] * aggh[(size_t)n * 320 + rem] : 0.f;
    }
    for (int t = tid; t < 16 * 128; t += 256) {
        int pb = t >> 7, cc = t & 127;
        float4 w;
        w.x = Wu0[(4 * pb + 0) * 128 + cc];
        w.y = Wu0[(4 * pb + 1) * 128 + cc];
        w.z = Wu0[(4 * pb + 2) * 128 + cc];
        w.w = Wu0[(4 * pb + 3) * 128 + cc];
        Ws[t] = w;
    }
    __syncthreads();

    int c = tid & 63;      // owns cols c and c+64 (of 128)
    int r0 = (tid >> 6) * 4;

    // ---- l0 ----
    {
        float b0 = bu0[c], b1 = bu0[c + 64];
        float A0[4], A1[4];
#pragma unroll
        for (int r = 0; r < 4; r++) { A0[r] = b0; A1[r] = b1; }
        for (int pb = 0; pb < 16; pb++) {
            const float4 w0 = Ws[pb * 128 + c];
            const float4 w1 = Ws[pb * 128 + c + 64];
#pragma unroll
            for (int r = 0; r < 4; r++) {
                const float4 av = *(const float4*)&a0s[(r0 + r) * 64 + pb * 4];
                A0[r] += av.x * w0.x + av.y * w0.y + av.z * w0.z + av.w * w0.w;
                A1[r] += av.x * w1.x + av.y * w1.y + av.z * w1.z + av.w * w1.w;
            }
        }
#pragma unroll
        for (int r = 0; r < 4; r++) {
            int n = n0 + r0 + r;
            if (n < N) {
                node[(size_t)n * 384 + c]      = A0[r];
                node[(size_t)n * 384 + c + 64] = A1[r];
            }
        }
    }
    __syncthreads();
    // ---- restage Wu1 ----
    for (int t = tid; t < 16 * 128; t += 256) {
        int pb = t >> 7, cc = t & 127;
        float4 w;
        w.x = Wu1[(4 * pb + 0) * 128 + cc];
        w.y = Wu1[(4 * pb + 1) * 128 + cc];
        w.z = Wu1[(4 * pb + 2) * 128 + cc];
        w.w = Wu1[(4 * pb + 3) * 128 + cc];
        Ws[t] = w;
    }
    __syncthreads();
    // ---- l1 ----
    {
        float S0[4], S1[4];
#pragma unroll
        for (int r = 0; r < 4; r++) { S0[r] = 0.f; S1[r] = 0.f; }
        for (int cc = 0; cc < 3; cc++) {
            float D0[4], D1[4];
#pragma unroll
            for (int r = 0; r < 4; r++) { D0[r] = 0.f; D1[r] = 0.f; }
            for (int pb = 0; pb < 16; pb++) {
                const float4 w0 = Ws[pb * 128 + c];
                const float4 w1 = Ws[pb * 128 + c + 64];
#pragma unroll
                for (int r = 0; r < 4; r++) {
                    const float4 av = *(const float4*)&a1s[((r0 + r) * 3 + cc) * 64 + pb * 4];
                    D0[r] += av.x * w0.x + av.y * w0.y + av.z * w0.z + av.w * w0.w;
                    D1[r] += av.x * w1.x + av.y * w1.y + av.z * w1.z + av.w * w1.w;
                }
            }
#pragma unroll
            for (int r = 0; r < 4; r++) { S0[r] += D0[r] * D0[r]; S1[r] += D1[r] * D1[r]; }
        }
#pragma unroll
        for (int r = 0; r < 4; r++) {
            int n = n0 + r0 + r;
            if (n < N) {
                node[(size_t)n * 384 + 128 + c]      = S0[r];
                node[(size_t)n * 384 + 128 + c + 64] = S1[r];
            }
        }
    }
    __syncthreads();
    // ---- restage Wuh ----
    for (int t = tid; t < 16 * 128; t += 256) {
        int pb = t >> 7, cc = t & 127;
        float4 w;
        w.x = Wuh[(4 * pb + 0) * 128 + cc];
        w.y = Wuh[(4 * pb + 1) * 128 + cc];
        w.z = Wuh[(4 * pb + 2) * 128 + cc];
        w.w = Wuh[(4 * pb + 3) * 128 + cc];
        Ws[t] = w;
    }
    __syncthreads();
    // ---- lh ----
    {
        float S0[4], S1[4];
#pragma unroll
        for (int r = 0; r < 4; r++) { S0[r] = 0.f; S1[r] = 0.f; }
        for (int cc = 0; cc < 5; cc++) {
            float D0[4], D1[4];
#pragma unroll
            for (int r = 0; r < 4; r++) { D0[r] = 0.f; D1[r] = 0.f; }
            for (int pb = 0; pb < 16; pb++) {
                const float4 w0 = Ws[pb * 128 + c];
                const float4 w1 = Ws[pb * 128 + c + 64];
#pragma unroll
                for (int r = 0; r < 4; r++) {
                    const float4 av = *(const float4*)&ahs[((r0 + r) * 5 + cc) * 64 + pb * 4];
                    D0[r] += av.x * w0.x + av.y * w0.y + av.z * w0.z + av.w * w0.w;
                    D1[r] += av.x * w1.x + av.y * w1.y + av.z * w1.z + av.w * w1.w;
                }
            }
#pragma unroll
            for (int r = 0; r < 4; r++) { S0[r] += D0[r] * D0[r]; S1[r] += D1[r] * D1[r]; }
        }
#pragma unroll
        for (int r = 0; r < 4; r++) {
            int n = n0 + r0 + r;
            if (n < N) {
                node[(size_t)n * 384 + 256 + c]      = S0[r];
                node[(size_t)n * 384 + 256 + c + 64] = S1[r];
            }
        }
    }
}

// ---------------------------------------------------------------------------
// Stage C2 (fused): unchanged this round — attribution isolation.
// ---------------------------------------------------------------------------
#define C2_ROWS 32
__global__ __launch_bounds__(256) void k_final(
    const float* __restrict__ node, const float* __restrict__ Wn1,
    const float* __restrict__ bn1, const float* __restrict__ lng,
    const float* __restrict__ lnb, const float* __restrict__ Wn2,
    const float* __restrict__ bn2, const float* __restrict__ x,
    float* __restrict__ out, int N)
{
    __shared__ float As[C2_ROWS][32];
    __shared__ float Hs[C2_ROWS][256];
    __shared__ float red[C2_ROWS][8];
    __shared__ float red2[C2_ROWS][8];
    __shared__ float mstat[C2_ROWS][2];

    int n0 = blockIdx.x * C2_ROWS;
    int tid = threadIdx.x;
    int c2 = tid & 127;
    int g = tid >> 7;
    int r0 = g * 16;

    float acc0[16], acc1[16];
#pragma unroll
    for (int r = 0; r < 16; r++) { acc0[r] = 0.f; acc1[r] = 0.f; }

    for (int k0 = 0; k0 < 384; k0 += 32) {
        for (int t = tid; t < C2_ROWS * 32; t += 256) {
            int r = t >> 5, k = t & 31;
            int n = n0 + r;
            As[r][k] = (n < N) ? node[(size_t)n * 384 + k0 + k] : 0.f;
        }
        __syncthreads();
        for (int k = 0; k < 32; k += 4) {
            float w00 = Wn1[(k0 + k + 0) * 256 + c2];
            float w01 = Wn1[(k0 + k + 1) * 256 + c2];
            float w02 = Wn1[(k0 + k + 2) * 256 + c2];
            float w03 = Wn1[(k0 + k + 3) * 256 + c2];
            float w10 = Wn1[(k0 + k + 0) * 256 + c2 + 128];
            float w11 = Wn1[(k0 + k + 1) * 256 + c2 + 128];
            float w12 = Wn1[(k0 + k + 2) * 256 + c2 + 128];
            float w13 = Wn1[(k0 + k + 3) * 256 + c2 + 128];
#pragma unroll
            for (int r = 0; r < 16; r++) {
                const float4 av = *(const float4*)&As[r0 + r][k];
                acc0[r] += av.x * w00 + av.y * w01 + av.z * w02 + av.w * w03;
                acc1[r] += av.x * w10 + av.y * w11 + av.z * w12 + av.w * w13;
            }
        }
        __syncthreads();
    }

    {
        float b0 = bn1[c2], b1 = bn1[c2 + 128];
#pragma unroll
        for (int r = 0; r < 16; r++) {
            Hs[r0 + r][c2]       = acc0[r] + b0;
            Hs[r0 + r][c2 + 128] = acc1[r] + b1;
        }
    }
    __syncthreads();

    {
        int row = tid >> 3, seg = tid & 7;
        float s = 0.f, s2 = 0.f;
#pragma unroll
        for (int k = 0; k < 32; k += 4) {
            const float4 v = *(const float4*)&Hs[row][seg * 32 + k];
            s  += v.x + v.y + v.z + v.w;
            s2 += v.x * v.x + v.y * v.y + v.z * v.z + v.w * v.w;
        }
        red[row][seg] = s;
        red2[row][seg] = s2;
    }
    __syncthreads();
    if (tid < C2_ROWS) {
        float s = 0.f, s2 = 0.f;
#pragma unroll
        for (int q = 0; q < 8; q++) { s += red[tid][q]; s2 += red2[tid][q]; }
        float m = s * (1.f / 256.f);
        float var = s2 * (1.f / 256.f) - m * m;
        mstat[tid][0] = m;
        mstat[tid][1] = rsqrtf(var + 1e-5f);
    }
    __syncthreads();

    {
        float g0 = lng[c2], g1 = lng[c2 + 128];
        float bb0 = lnb[c2], bb1 = lnb[c2 + 128];
#pragma unroll
        for (int r = 0; r < 16; r++) {
            int row = r0 + r;
            float m = mstat[row][0], is = mstat[row][1];
            float z0 = (Hs[row][c2] - m) * is * g0 + bb0;
            float z1 = (Hs[row][c2 + 128] - m) * is * g1 + bb1;
            Hs[row][c2]       = z0 / (1.f + __expf(-z0));
            Hs[row][c2 + 128] = z1 / (1.f + __expf(-z1));
        }
    }
    __syncthreads();

    float o0[16], o1[16];
#pragma unroll
    for (int r = 0; r < 16; r++) { o0[r] = 0.f; o1[r] = 0.f; }
    for (int k = 0; k < 256; k += 4) {
        float w00 = Wn2[(k + 0) * 256 + c2];
        float w01 = Wn2[(k + 1) * 256 + c2];
        float w02 = Wn2[(k + 2) * 256 + c2];
        float w03 = Wn2[(k + 3) * 256 + c2];
        float w10 = Wn2[(k + 0) * 256 + c2 + 128];
        float w11 = Wn2[(k + 1) * 256 + c2 + 128];
        float w12 = Wn2[(k + 2) * 256 + c2 + 128];
        float w13 = Wn2[(k + 3) * 256 + c2 + 128];
#pragma unroll
        for (int r = 0; r < 16; r++) {
            const float4 av = *(const float4*)&Hs[r0 + r][k];
            o0[r] += av.x * w00 + av.y * w01 + av.z * w02 + av.w * w03;
            o1[r] += av.x * w10 + av.y * w11 + av.z * w12 + av.w * w13;
        }
    }
    {
        float ob0 = bn2[c2], ob1 = bn2[c2 + 128];
#pragma unroll
        for (int r = 0; r < 16; r++) {
            int n = n0 + r0 + r;
            if (n < N) {
                out[(size_t)n * 256 + c2]       = o0[r] + ob0 + x[(size_t)n * 256 + c2];
                out[(size_t)n * 256 + c2 + 128] = o1[r] + ob1 + x[(size_t)n * 256 + c2 + 128];
            }
        }
    }
}

// ---------------------------------------------------------------------------
extern "C" void kernel_launch(void* const* d_in, const int* in_sizes, int n_in,
                              void* d_out, int out_size, void* d_ws, size_t ws_size,
                              hipStream_t stream)
{
    const float* x      = (const float*)d_in[0];
    const float* rbf    = (const float*)d_in[1];
    const float* factor = (const float*)d_in[2];
    const float* sph0   = (const float*)d_in[3];
    const float* sph1   = (const float*)d_in[4];
    const float* Wd     = (const float*)d_in[5];
    const float* bd     = (const float*)d_in[6];
    const float* Wu0    = (const float*)d_in[7];
    const float* bu0    = (const float*)d_in[8];
    const float* Wu1    = (const float*)d_in[9];
    const float* Wuh    = (const float*)d_in[10];
    const float* Wn1    = (const float*)d_in[11];
    const float* bn1    = (const float*)d_in[12];
    const float* lng    = (const float*)d_in[13];
    const float* lnb    = (const float*)d_in[14];
    const float* Wn2    = (const float*)d_in[15];
    const float* bn2    = (const float*)d_in[16];
    const int*   jidx   = (const int*)d_in[17];
    const int*   iidx   = (const int*)d_in[18];
    float* out = (float*)d_out;

    int N = in_sizes[0] / 256;
    int E = in_sizes[17];

    float* ws   = (float*)d_ws;
    float* xp   = ws;                        // [N,64]
    float* agg0 = xp   + (size_t)N * 64;     // [N,64]
    float* agg1 = agg0 + (size_t)N * 64;     // [N,3,64]
    float* aggh = agg1 + (size_t)N * 192;    // [N,5,64]
    float* node = aggh + (size_t)N * 320;    // [N,384]

    hipMemsetAsync(agg0, 0, (size_t)N * 576 * sizeof(float), stream);

    k_down<<<dim3((N + KD_NODES - 1) / KD_NODES), dim3(256), 0, stream>>>(
        x, Wd, bd, xp, N);
    k_edge<<<dim3((E + 3) / 4), dim3(256), 0, stream>>>(
        xp, rbf, factor, sph0, sph1, jidx, iidx, agg0, agg1, aggh, E);
    k_node<<<dim3((N + C1_NODES - 1) / C1_NODES), dim3(256), 0, stream>>>(
        xp, agg0, agg1, aggh, Wu0, bu0, Wu1, Wuh, node, N);
    k_final<<<dim3((N + C2_ROWS - 1) / C2_ROWS), dim3(256), 0, stream>>>(
        node, Wn1, bn1, lng, lnb, Wn2, bn2, x, out, N);
}

// Round 4
// 966.637 us; speedup vs baseline: 4.0315x; 1.6954x over previous
//
#include <hip/hip_runtime.h>
#include <hip/hip_bf16.h>

// ---------------------------------------------------------------------------
// Stage A: _x = x @ W_down + b_down    [N,256]@[256,64] -> [N,64]
// Wd staged in LDS once per block (R2). 8 nodes/block.
// ---------------------------------------------------------------------------
#define KD_NODES 8
__global__ __launch_bounds__(256) void k_down(
    const float* __restrict__ x, const float* __restrict__ Wd,
    const float* __restrict__ bd, float* __restrict__ xp, int N)
{
    __shared__ float xs[KD_NODES][256];   // 8 KB
    __shared__ float4 Ws[64 * 64];        // 64 KB: Ws[pb*64+c] = Wd[4pb+q][c]
    int n0 = blockIdx.x * KD_NODES;
    int tid = threadIdx.x;

    for (int t = tid; t < KD_NODES * 256; t += 256) {
        int rr = t >> 8, kk = t & 255;
        int n = n0 + rr;
        xs[rr][kk] = (n < N) ? x[(size_t)n * 256 + kk] : 0.f;
    }
    for (int t = tid; t < 64 * 64; t += 256) {
        int pb = t >> 6, c = t & 63;
        float4 w;
        w.x = Wd[(4 * pb + 0) * 64 + c];
        w.y = Wd[(4 * pb + 1) * 64 + c];
        w.z = Wd[(4 * pb + 2) * 64 + c];
        w.w = Wd[(4 * pb + 3) * 64 + c];
        Ws[t] = w;
    }
    __syncthreads();

    int c = tid & 63;
    int r0 = (tid >> 6) * 2;
    float a0 = bd[c], a1 = a0;
    for (int pb = 0; pb < 64; pb++) {
        float4 w = Ws[pb * 64 + c];
        const float4 x0 = *(const float4*)&xs[r0][pb * 4];
        const float4 x1 = *(const float4*)&xs[r0 + 1][pb * 4];
        a0 += x0.x * w.x + x0.y * w.y + x0.z * w.z + x0.w * w.w;
        a1 += x1.x * w.x + x1.y * w.y + x1.z * w.z + x1.w * w.w;
    }
    int n = n0 + r0;
    if (n < N)     xp[(size_t)n * 64 + c]       = a0;
    if (n + 1 < N) xp[(size_t)(n + 1) * 64 + c] = a1;
}

// ---------------------------------------------------------------------------
// Stage B (R3 rewrite): scatter-atomics -> CSR build + per-node gather.
// Was: 288M f32 atomicAdds = 1.125 GB fabric writes, 886 us at ~1.5 TB/s.
// Now: 1M int atomics (hist+scatter) + one wave per node accumulating its
// edges in registers, each agg row written exactly once (57.6 MB).
// ---------------------------------------------------------------------------
__global__ __launch_bounds__(256) void k_hist(
    const int* __restrict__ iidx, int* __restrict__ counts, int E)
{
    int e = blockIdx.x * 256 + threadIdx.x;
    if (e < E) atomicAdd(&counts[iidx[e]], 1);
}

// one block, 1024 threads: exclusive prefix sum of counts[0..N) -> rowptr,
// plus a second copy in cursor for the scatter pass. rowptr[N] = E.
__global__ __launch_bounds__(1024) void k_scan(
    const int* __restrict__ counts, int* __restrict__ rowptr,
    int* __restrict__ cursor, int N)
{
    __shared__ int part[1024];
    int t = threadIdx.x;
    int chunk = (N + 1023) / 1024;
    int beg = t * chunk;
    int end = min(beg + chunk, N);
    int s = 0;
    for (int i = beg; i < end; i++) s += counts[i];
    part[t] = s;
    __syncthreads();
    for (int off = 1; off < 1024; off <<= 1) {
        int v = (t >= off) ? part[t - off] : 0;
        __syncthreads();
        part[t] += v;
        __syncthreads();
    }
    int run = (t == 0) ? 0 : part[t - 1];
    for (int i = beg; i < end; i++) {
        rowptr[i] = run;
        cursor[i] = run;
        run += counts[i];
    }
    if (t == 1023) rowptr[N] = part[1023];
}

__global__ __launch_bounds__(256) void k_scatter_ids(
    const int* __restrict__ iidx, int* __restrict__ cursor,
    int* __restrict__ edge_id, int E)
{
    int e = blockIdx.x * 256 + threadIdx.x;
    if (e < E) {
        int pos = atomicAdd(&cursor[iidx[e]], 1);
        edge_id[pos] = e;
    }
}

// one wave per node; lane = channel p. 9 register accumulators.
__global__ __launch_bounds__(256) void k_gather(
    const float* __restrict__ xp, const float* __restrict__ rbf,
    const float* __restrict__ factor, const float* __restrict__ sph0,
    const float* __restrict__ sph1, const int* __restrict__ jidx,
    const int* __restrict__ rowptr, const int* __restrict__ edge_id,
    float* __restrict__ agg0, float* __restrict__ agg1,
    float* __restrict__ aggh, int N)
{
    int n = blockIdx.x * 4 + (threadIdx.x >> 6);
    if (n >= N) return;
    int p = threadIdx.x & 63;
    int beg = rowptr[n], end = rowptr[n + 1];

    float a0 = 0.f;
    float a1x = 0.f, a1y = 0.f, a1z = 0.f;
    float h0 = 0.f, h1 = 0.f, h2 = 0.f, h3 = 0.f, h4 = 0.f;

    int k = beg;
    for (; k + 1 < end; k += 2) {
        int e0 = edge_id[k], e1 = edge_id[k + 1];
        int j0 = jidx[e0], j1 = jidx[e1];
        float f0 = factor[e0], f1 = factor[e1];
        float v0 = xp[(size_t)j0 * 64 + p] * rbf[(size_t)e0 * 64 + p] * f0;
        float v1 = xp[(size_t)j1 * 64 + p] * rbf[(size_t)e1 * 64 + p] * f1;
        a0 += v0 + v1;
        a1x += v0 * sph1[e0 * 3 + 0] + v1 * sph1[e1 * 3 + 0];
        a1y += v0 * sph1[e0 * 3 + 1] + v1 * sph1[e1 * 3 + 1];
        a1z += v0 * sph1[e0 * 3 + 2] + v1 * sph1[e1 * 3 + 2];
        h0  += v0 * sph0[e0 * 5 + 0] + v1 * sph0[e1 * 5 + 0];
        h1  += v0 * sph0[e0 * 5 + 1] + v1 * sph0[e1 * 5 + 1];
        h2  += v0 * sph0[e0 * 5 + 2] + v1 * sph0[e1 * 5 + 2];
        h3  += v0 * sph0[e0 * 5 + 3] + v1 * sph0[e1 * 5 + 3];
        h4  += v0 * sph0[e0 * 5 + 4] + v1 * sph0[e1 * 5 + 4];
    }
    if (k < end) {
        int e0 = edge_id[k];
        int j0 = jidx[e0];
        float f0 = factor[e0];
        float v0 = xp[(size_t)j0 * 64 + p] * rbf[(size_t)e0 * 64 + p] * f0;
        a0 += v0;
        a1x += v0 * sph1[e0 * 3 + 0];
        a1y += v0 * sph1[e0 * 3 + 1];
        a1z += v0 * sph1[e0 * 3 + 2];
        h0  += v0 * sph0[e0 * 5 + 0];
        h1  += v0 * sph0[e0 * 5 + 1];
        h2  += v0 * sph0[e0 * 5 + 2];
        h3  += v0 * sph0[e0 * 5 + 3];
        h4  += v0 * sph0[e0 * 5 + 4];
    }

    agg0[(size_t)n * 64 + p] = a0;
    agg1[((size_t)n * 3 + 0) * 64 + p] = a1x;
    agg1[((size_t)n * 3 + 1) * 64 + p] = a1y;
    agg1[((size_t)n * 3 + 2) * 64 + p] = a1z;
    aggh[((size_t)n * 5 + 0) * 64 + p] = h0;
    aggh[((size_t)n * 5 + 1) * 64 + p] = h1;
    aggh[((size_t)n * 5 + 2) * 64 + p] = h2;
    aggh[((size_t)n * 5 + 3) * 64 + p] = h3;
    aggh[((size_t)n * 5 + 4) * 64 + p] = h4;
}

// ---------------------------------------------------------------------------
// Stage C1: node features -> node[N,384]  (unchanged from R2)
// ---------------------------------------------------------------------------
#define C1_NODES 16
__global__ __launch_bounds__(256) void k_node(
    const float* __restrict__ xp, const float* __restrict__ agg0,
    const float* __restrict__ agg1, const float* __restrict__ aggh,
    const float* __restrict__ Wu0, const float* __restrict__ bu0,
    const float* __restrict__ Wu1, const float* __restrict__ Wuh,
    float* __restrict__ node, int N)
{
    __shared__ float xs[C1_NODES * 64];
    __shared__ float a0s[C1_NODES * 64];
    __shared__ float a1s[C1_NODES * 3 * 64];
    __shared__ float ahs[C1_NODES * 5 * 64];
    __shared__ float4 Ws[16 * 128];
    int n0 = blockIdx.x * C1_NODES;
    int tid = threadIdx.x;

    for (int t = tid; t < C1_NODES * 64; t += 256) {
        int n = n0 + (t >> 6);
        xs[t] = (n < N) ? xp[(size_t)n * 64 + (t & 63)] : 0.f;
    }
    __syncthreads();
    for (int t = tid; t < C1_NODES * 64; t += 256) {
        int n = n0 + (t >> 6);
        a0s[t] = (n < N) ? xs[t] * agg0[(size_t)n * 64 + (t & 63)] : 0.f;
    }
    for (int t = tid; t < C1_NODES * 192; t += 256) {
        int r = t / 192, rem = t - r * 192;
        int n = n0 + r;
        a1s[t] = (n < N) ? xs[r * 64 + (rem & 63)] * agg1[(size_t)n * 192 + rem] : 0.f;
    }
    for (int t = tid; t < C1_NODES * 320; t += 256) {
        int r = t / 320, rem = t - r * 320;
        int n = n0 + r;
        ahs[t] = (n < N) ? xs[r * 64 + (rem & 63)] * aggh[(size_t)n * 320 + rem] : 0.f;
    }
    for (int t = tid; t < 16 * 128; t += 256) {
        int pb = t >> 7, cc = t & 127;
        float4 w;
        w.x = Wu0[(4 * pb + 0) * 128 + cc];
        w.y = Wu0[(4 * pb + 1) * 128 + cc];
        w.z = Wu0[(4 * pb + 2) * 128 + cc];
        w.w = Wu0[(4 * pb + 3) * 128 + cc];
        Ws[t] = w;
    }
    __syncthreads();

    int c = tid & 63;
    int r0 = (tid >> 6) * 4;

    // ---- l0 ----
    {
        float b0 = bu0[c], b1 = bu0[c + 64];
        float A0[4], A1[4];
#pragma unroll
        for (int r = 0; r < 4; r++) { A0[r] = b0; A1[r] = b1; }
        for (int pb = 0; pb < 16; pb++) {
            const float4 w0 = Ws[pb * 128 + c];
            const float4 w1 = Ws[pb * 128 + c + 64];
#pragma unroll
            for (int r = 0; r < 4; r++) {
                const float4 av = *(const float4*)&a0s[(r0 + r) * 64 + pb * 4];
                A0[r] += av.x * w0.x + av.y * w0.y + av.z * w0.z + av.w * w0.w;
                A1[r] += av.x * w1.x + av.y * w1.y + av.z * w1.z + av.w * w1.w;
            }
        }
#pragma unroll
        for (int r = 0; r < 4; r++) {
            int n = n0 + r0 + r;
            if (n < N) {
                node[(size_t)n * 384 + c]      = A0[r];
                node[(size_t)n * 384 + c + 64] = A1[r];
            }
        }
    }
    __syncthreads();
    for (int t = tid; t < 16 * 128; t += 256) {
        int pb = t >> 7, cc = t & 127;
        float4 w;
        w.x = Wu1[(4 * pb + 0) * 128 + cc];
        w.y = Wu1[(4 * pb + 1) * 128 + cc];
        w.z = Wu1[(4 * pb + 2) * 128 + cc];
        w.w = Wu1[(4 * pb + 3) * 128 + cc];
        Ws[t] = w;
    }
    __syncthreads();
    // ---- l1 ----
    {
        float S0[4], S1[4];
#pragma unroll
        for (int r = 0; r < 4; r++) { S0[r] = 0.f; S1[r] = 0.f; }
        for (int cc = 0; cc < 3; cc++) {
            float D0[4], D1[4];
#pragma unroll
            for (int r = 0; r < 4; r++) { D0[r] = 0.f; D1[r] = 0.f; }
            for (int pb = 0; pb < 16; pb++) {
                const float4 w0 = Ws[pb * 128 + c];
                const float4 w1 = Ws[pb * 128 + c + 64];
#pragma unroll
                for (int r = 0; r < 4; r++) {
                    const float4 av = *(const float4*)&a1s[((r0 + r) * 3 + cc) * 64 + pb * 4];
                    D0[r] += av.x * w0.x + av.y * w0.y + av.z * w0.z + av.w * w0.w;
                    D1[r] += av.x * w1.x + av.y * w1.y + av.z * w1.z + av.w * w1.w;
                }
            }
#pragma unroll
            for (int r = 0; r < 4; r++) { S0[r] += D0[r] * D0[r]; S1[r] += D1[r] * D1[r]; }
        }
#pragma unroll
        for (int r = 0; r < 4; r++) {
            int n = n0 + r0 + r;
            if (n < N) {
                node[(size_t)n * 384 + 128 + c]      = S0[r];
                node[(size_t)n * 384 + 128 + c + 64] = S1[r];
            }
        }
    }
    __syncthreads();
    for (int t = tid; t < 16 * 128; t += 256) {
        int pb = t >> 7, cc = t & 127;
        float4 w;
        w.x = Wuh[(4 * pb + 0) * 128 + cc];
        w.y = Wuh[(4 * pb + 1) * 128 + cc];
        w.z = Wuh[(4 * pb + 2) * 128 + cc];
        w.w = Wuh[(4 * pb + 3) * 128 + cc];
        Ws[t] = w;
    }
    __syncthreads();
    // ---- lh ----
    {
        float S0[4], S1[4];
#pragma unroll
        for (int r = 0; r < 4; r++) { S0[r] = 0.f; S1[r] = 0.f; }
        for (int cc = 0; cc < 5; cc++) {
            float D0[4], D1[4];
#pragma unroll
            for (int r = 0; r < 4; r++) { D0[r] = 0.f; D1[r] = 0.f; }
            for (int pb = 0; pb < 16; pb++) {
                const float4 w0 = Ws[pb * 128 + c];
                const float4 w1 = Ws[pb * 128 + c + 64];
#pragma unroll
                for (int r = 0; r < 4; r++) {
                    const float4 av = *(const float4*)&ahs[((r0 + r) * 5 + cc) * 64 + pb * 4];
                    D0[r] += av.x * w0.x + av.y * w0.y + av.z * w0.z + av.w * w0.w;
                    D1[r] += av.x * w1.x + av.y * w1.y + av.z * w1.z + av.w * w1.w;
                }
            }
#pragma unroll
            for (int r = 0; r < 4; r++) { S0[r] += D0[r] * D0[r]; S1[r] += D1[r] * D1[r]; }
        }
#pragma unroll
        for (int r = 0; r < 4; r++) {
            int n = n0 + r0 + r;
            if (n < N) {
                node[(size_t)n * 384 + 256 + c]      = S0[r];
                node[(size_t)n * 384 + 256 + c + 64] = S1[r];
            }
        }
    }
}

// ---------------------------------------------------------------------------
// Stage C2 (fused): unchanged this round — attribution isolation.
// ---------------------------------------------------------------------------
#define C2_ROWS 32
__global__ __launch_bounds__(256) void k_final(
    const float* __restrict__ node, const float* __restrict__ Wn1,
    const float* __restrict__ bn1, const float* __restrict__ lng,
    const float* __restrict__ lnb, const float* __restrict__ Wn2,
    const float* __restrict__ bn2, const float* __restrict__ x,
    float* __restrict__ out, int N)
{
    __shared__ float As[C2_ROWS][32];
    __shared__ float Hs[C2_ROWS][256];
    __shared__ float red[C2_ROWS][8];
    __shared__ float red2[C2_ROWS][8];
    __shared__ float mstat[C2_ROWS][2];

    int n0 = blockIdx.x * C2_ROWS;
    int tid = threadIdx.x;
    int c2 = tid & 127;
    int g = tid >> 7;
    int r0 = g * 16;

    float acc0[16], acc1[16];
#pragma unroll
    for (int r = 0; r < 16; r++) { acc0[r] = 0.f; acc1[r] = 0.f; }

    for (int k0 = 0; k0 < 384; k0 += 32) {
        for (int t = tid; t < C2_ROWS * 32; t += 256) {
            int r = t >> 5, k = t & 31;
            int n = n0 + r;
            As[r][k] = (n < N) ? node[(size_t)n * 384 + k0 + k] : 0.f;
        }
        __syncthreads();
        for (int k = 0; k < 32; k += 4) {
            float w00 = Wn1[(k0 + k + 0) * 256 + c2];
            float w01 = Wn1[(k0 + k + 1) * 256 + c2];
            float w02 = Wn1[(k0 + k + 2) * 256 + c2];
            float w03 = Wn1[(k0 + k + 3) * 256 + c2];
            float w10 = Wn1[(k0 + k + 0) * 256 + c2 + 128];
            float w11 = Wn1[(k0 + k + 1) * 256 + c2 + 128];
            float w12 = Wn1[(k0 + k + 2) * 256 + c2 + 128];
            float w13 = Wn1[(k0 + k + 3) * 256 + c2 + 128];
#pragma unroll
            for (int r = 0; r < 16; r++) {
                const float4 av = *(const float4*)&As[r0 + r][k];
                acc0[r] += av.x * w00 + av.y * w01 + av.z * w02 + av.w * w03;
                acc1[r] += av.x * w10 + av.y * w11 + av.z * w12 + av.w * w13;
            }
        }
        __syncthreads();
    }

    {
        float b0 = bn1[c2], b1 = bn1[c2 + 128];
#pragma unroll
        for (int r = 0; r < 16; r++) {
            Hs[r0 + r][c2]       = acc0[r] + b0;
            Hs[r0 + r][c2 + 128] = acc1[r] + b1;
        }
    }
    __syncthreads();

    {
        int row = tid >> 3, seg = tid & 7;
        float s = 0.f, s2 = 0.f;
#pragma unroll
        for (int k = 0; k < 32; k += 4) {
            const float4 v = *(const float4*)&Hs[row][seg * 32 + k];
            s  += v.x + v.y + v.z + v.w;
            s2 += v.x * v.x + v.y * v.y + v.z * v.z + v.w * v.w;
        }
        red[row][seg] = s;
        red2[row][seg] = s2;
    }
    __syncthreads();
    if (tid < C2_ROWS) {
        float s = 0.f, s2 = 0.f;
#pragma unroll
        for (int q = 0; q < 8; q++) { s += red[tid][q]; s2 += red2[tid][q]; }
        float m = s * (1.f / 256.f);
        float var = s2 * (1.f / 256.f) - m * m;
        mstat[tid][0] = m;
        mstat[tid][1] = rsqrtf(var + 1e-5f);
    }
    __syncthreads();

    {
        float g0 = lng[c2], g1 = lng[c2 + 128];
        float bb0 = lnb[c2], bb1 = lnb[c2 + 128];
#pragma unroll
        for (int r = 0; r < 16; r++) {
            int row = r0 + r;
            float m = mstat[row][0], is = mstat[row][1];
            float z0 = (Hs[row][c2] - m) * is * g0 + bb0;
            float z1 = (Hs[row][c2 + 128] - m) * is * g1 + bb1;
            Hs[row][c2]       = z0 / (1.f + __expf(-z0));
            Hs[row][c2 + 128] = z1 / (1.f + __expf(-z1));
        }
    }
    __syncthreads();

    float o0[16], o1[16];
#pragma unroll
    for (int r = 0; r < 16; r++) { o0[r] = 0.f; o1[r] = 0.f; }
    for (int k = 0; k < 256; k += 4) {
        float w00 = Wn2[(k + 0) * 256 + c2];
        float w01 = Wn2[(k + 1) * 256 + c2];
        float w02 = Wn2[(k + 2) * 256 + c2];
        float w03 = Wn2[(k + 3) * 256 + c2];
        float w10 = Wn2[(k + 0) * 256 + c2 + 128];
        float w11 = Wn2[(k + 1) * 256 + c2 + 128];
        float w12 = Wn2[(k + 2) * 256 + c2 + 128];
        float w13 = Wn2[(k + 3) * 256 + c2 + 128];
#pragma unroll
        for (int r = 0; r < 16; r++) {
            const float4 av = *(const float4*)&Hs[r0 + r][k];
            o0[r] += av.x * w00 + av.y * w01 + av.z * w02 + av.w * w03;
            o1[r] += av.x * w10 + av.y * w11 + av.z * w12 + av.w * w13;
        }
    }
    {
        float ob0 = bn2[c2], ob1 = bn2[c2 + 128];
#pragma unroll
        for (int r = 0; r < 16; r++) {
            int n = n0 + r0 + r;
            if (n < N) {
                out[(size_t)n * 256 + c2]       = o0[r] + ob0 + x[(size_t)n * 256 + c2];
                out[(size_t)n * 256 + c2 + 128] = o1[r] + ob1 + x[(size_t)n * 256 + c2 + 128];
            }
        }
    }
}

// ---------------------------------------------------------------------------
extern "C" void kernel_launch(void* const* d_in, const int* in_sizes, int n_in,
                              void* d_out, int out_size, void* d_ws, size_t ws_size,
                              hipStream_t stream)
{
    const float* x      = (const float*)d_in[0];
    const float* rbf    = (const float*)d_in[1];
    const float* factor = (const float*)d_in[2];
    const float* sph0   = (const float*)d_in[3];
    const float* sph1   = (const float*)d_in[4];
    const float* Wd     = (const float*)d_in[5];
    const float* bd     = (const float*)d_in[6];
    const float* Wu0    = (const float*)d_in[7];
    const float* bu0    = (const float*)d_in[8];
    const float* Wu1    = (const float*)d_in[9];
    const float* Wuh    = (const float*)d_in[10];
    const float* Wn1    = (const float*)d_in[11];
    const float* bn1    = (const float*)d_in[12];
    const float* lng    = (const float*)d_in[13];
    const float* lnb    = (const float*)d_in[14];
    const float* Wn2    = (const float*)d_in[15];
    const float* bn2    = (const float*)d_in[16];
    const int*   jidx   = (const int*)d_in[17];
    const int*   iidx   = (const int*)d_in[18];
    float* out = (float*)d_out;

    int N = in_sizes[0] / 256;
    int E = in_sizes[17];

    float* ws   = (float*)d_ws;
    float* xp   = ws;                        // [N,64]
    float* agg0 = xp   + (size_t)N * 64;     // [N,64]
    float* agg1 = agg0 + (size_t)N * 64;     // [N,3,64]
    float* aggh = agg1 + (size_t)N * 192;    // [N,5,64]
    float* node = aggh + (size_t)N * 320;    // [N,384]

    // CSR scratch aliased onto the node buffer: edge_id/rowptr are dead
    // before k_node writes node (stream-ordered), so no extra ws footprint.
    int* counts  = (int*)node;               // [N]
    int* rowptr  = counts + (N + 1);         // [N+1]
    int* cursor  = rowptr + (N + 1);         // [N]
    int* edge_id = cursor + (N + 1);         // [E]

    hipMemsetAsync(counts, 0, (size_t)(N + 1) * sizeof(int), stream);

    k_down<<<dim3((N + KD_NODES - 1) / KD_NODES), dim3(256), 0, stream>>>(
        x, Wd, bd, xp, N);
    k_hist<<<dim3((E + 255) / 256), dim3(256), 0, stream>>>(iidx, counts, E);
    k_scan<<<dim3(1), dim3(1024), 0, stream>>>(counts, rowptr, cursor, N);
    k_scatter_ids<<<dim3((E + 255) / 256), dim3(256), 0, stream>>>(
        iidx, cursor, edge_id, E);
    k_gather<<<dim3((N + 3) / 4), dim3(256), 0, stream>>>(
        xp, rbf, factor, sph0, sph1, jidx, rowptr, edge_id,
        agg0, agg1, aggh, N);
    k_node<<<dim3((N + C1_NODES - 1) / C1_NODES), dim3(256), 0, stream>>>(
        xp, agg0, agg1, aggh, Wu0, bu0, Wu1, Wuh, node, N);
    k_final<<<dim3((N + C2_ROWS - 1) / C2_ROWS), dim3(256), 0, stream>>>(
        node, Wn1, bn1, lng, lnb, Wn2, bn2, x, out, N);
}